// Round 3
// baseline (590.547 us; speedup 1.0000x reference)
//
#include <hip/hip_runtime.h>
#include <hip/hip_bf16.h>

#define TT 2048
#define BB 512
#define HH 32
#define NPAIR (TT * BB)
#define PSTRIDE (BB * HH)   // floats per t-slice of P = 16384

// tanh(u) = 1 - 2/(1+e^{2u}); exact at both saturations (exp2->0 => -1, ->inf => +1).
// v_exp_f32 + v_rcp_f32: ~1 ulp each, chain ~28 cyc, no div sequence, no sign logic.
__device__ __forceinline__ float fast_tanh(float u) {
    float e = exp2f(u * 2.88539008177792681f);          // e^{2u} via v_exp_f32
    return 1.0f - 2.0f * __builtin_amdgcn_rcpf(e + 1.0f);
}

// ---------------- Pass 1: P[t][row][j] = b[j] + emb[x[t,row]] @ Wx[:,j] ----------------
// 16 contiguous pairs per 32-lane group; 64K waves => 8x oversubscription, TLP hides the
// idx->gather dependency chain. No pipelining needed.
#define PPG 16
template <bool FP32>
__global__ __launch_bounds__(256) void precompute_v3(
        const int* __restrict__ x, const float* __restrict__ emb,
        const float* __restrict__ W_rnn, const float* __restrict__ b_rnn,
        void* __restrict__ Pv) {
    float*          Pf = (float*)Pv;
    __hip_bfloat16* Ph = (__hip_bfloat16*)Pv;
    const int lane = threadIdx.x & 31;
    const int g    = (blockIdx.x * blockDim.x + threadIdx.x) >> 5;

    float wx[32];
#pragma unroll
    for (int k = 0; k < 32; ++k) wx[k] = W_rnn[k * HH + lane];
    const float bj = b_rnn[lane];

    const int pair0 = g * PPG;
#pragma unroll 2
    for (int i = 0; i < PPG; ++i) {
        const int pair = pair0 + i;
        const int idx  = x[pair];
        const float4* ep = (const float4*)(emb + (size_t)idx * HH);
        float u0 = bj, u1 = 0.f, u2 = 0.f, u3 = 0.f;
#pragma unroll
        for (int q = 0; q < 8; ++q) {
            float4 e = ep[q];   // broadcast load: same addr across the 32-lane group
            u0 = fmaf(e.x, wx[4*q+0], u0);
            u1 = fmaf(e.y, wx[4*q+1], u1);
            u2 = fmaf(e.z, wx[4*q+2], u2);
            u3 = fmaf(e.w, wx[4*q+3], u3);
        }
        float u = (u0 + u1) + (u2 + u3);
        if (FP32) Pf[(size_t)pair * HH + lane] = u;
        else      Ph[(size_t)pair * HH + lane] = __float2bfloat16(u);
    }
}

// ---------------- Pass 2: sequential scan, 2 rows per wave (one per 32-lane half) ------
// h-broadcast through LDS: 1 ds_write + 8 ds_read_b128 serve BOTH rows (per-lane addrs
// differ per half). Single-wave block: DS pipe ordering => no barriers anywhere.
template <bool FP32>
__global__ __launch_bounds__(64) void rnn_seq_v3(
        const void* __restrict__ Pv, const float* __restrict__ W_rnn,
        const float* __restrict__ W_cls, const float* __restrict__ b_cls,
        float* __restrict__ out) {
    const int jj   = threadIdx.x & 31;
    const int half = threadIdx.x >> 5;
    const int row  = blockIdx.x * 2 + half;

    float wh[32];
#pragma unroll
    for (int k = 0; k < 32; ++k) wh[k] = W_rnn[(HH + k) * HH + jj];

    __shared__ __align__(16) float hbuf[2][HH];
    hbuf[half][jj] = 0.0f;
    const float4* hp = (const float4*)&hbuf[half][0];

    const float*          Pf = (const float*)Pv;
    const __hip_bfloat16* Ph = (const __hip_bfloat16*)Pv;
    const size_t base = (size_t)row * HH + jj;

    // 8-deep static-address prefetch ring for p_t (issued 8 steps ahead of use).
    float p[8];
#pragma unroll
    for (int d = 0; d < 8; ++d)
        p[d] = FP32 ? Pf[(size_t)d * PSTRIDE + base]
                    : __bfloat162float(Ph[(size_t)d * PSTRIDE + base]);

    for (int t = 0; t < TT; t += 8) {
#pragma unroll
        for (int d = 0; d < 8; ++d) {
            float u0 = p[d];
            int tn = t + d + 8;
            if (tn > TT - 1) tn = TT - 1;
            size_t off = (size_t)tn * PSTRIDE + base;
            p[d] = FP32 ? Pf[off] : __bfloat162float(Ph[off]);

            // 8 accumulators: FMA depth 4 + 3-level tree (was depth 8 + 2)
            float u1 = 0.f, u2 = 0.f, u3 = 0.f, u4 = 0.f, u5 = 0.f, u6 = 0.f, u7 = 0.f;
            float4 h0 = hp[0], h1 = hp[1], h2 = hp[2], h3 = hp[3];
            float4 h4 = hp[4], h5 = hp[5], h6 = hp[6], h7 = hp[7];
            u0 = fmaf(h0.x, wh[ 0], u0); u1 = fmaf(h0.y, wh[ 1], u1);
            u2 = fmaf(h0.z, wh[ 2], u2); u3 = fmaf(h0.w, wh[ 3], u3);
            u4 = fmaf(h1.x, wh[ 4], u4); u5 = fmaf(h1.y, wh[ 5], u5);
            u6 = fmaf(h1.z, wh[ 6], u6); u7 = fmaf(h1.w, wh[ 7], u7);
            u0 = fmaf(h2.x, wh[ 8], u0); u1 = fmaf(h2.y, wh[ 9], u1);
            u2 = fmaf(h2.z, wh[10], u2); u3 = fmaf(h2.w, wh[11], u3);
            u4 = fmaf(h3.x, wh[12], u4); u5 = fmaf(h3.y, wh[13], u5);
            u6 = fmaf(h3.z, wh[14], u6); u7 = fmaf(h3.w, wh[15], u7);
            u0 = fmaf(h4.x, wh[16], u0); u1 = fmaf(h4.y, wh[17], u1);
            u2 = fmaf(h4.z, wh[18], u2); u3 = fmaf(h4.w, wh[19], u3);
            u4 = fmaf(h5.x, wh[20], u4); u5 = fmaf(h5.y, wh[21], u5);
            u6 = fmaf(h5.z, wh[22], u6); u7 = fmaf(h5.w, wh[23], u7);
            u0 = fmaf(h6.x, wh[24], u0); u1 = fmaf(h6.y, wh[25], u1);
            u2 = fmaf(h6.z, wh[26], u2); u3 = fmaf(h6.w, wh[27], u3);
            u4 = fmaf(h7.x, wh[28], u4); u5 = fmaf(h7.y, wh[29], u5);
            u6 = fmaf(h7.z, wh[30], u6); u7 = fmaf(h7.w, wh[31], u7);
            float u = ((u0 + u1) + (u2 + u3)) + ((u4 + u5) + (u6 + u7));
            float hn = fast_tanh(u);
            hbuf[half][jj] = hn;    // in-wave DS ordering: reads above complete first
        }
    }

    // Epilogue: y = h @ W_cls + b_cls (N_CLASS=5). Compute on all lanes (clamped col),
    // store only lanes jj<5 of each half.
    {
        const int c = (jj < 5) ? jj : 0;
        float acc = b_cls[c];
#pragma unroll
        for (int k = 0; k < 32; ++k)
            acc = fmaf(hbuf[half][k], W_cls[k * 5 + c], acc);
        if (jj < 5) out[row * 5 + jj] = acc;
    }
}

// ---------------- Fallback (R1 fused kernel) for tiny workspace ------------------------
__device__ __forceinline__ float rnn_step_fb(const float4 xt[8], const float wx[32],
                                             const float wh[32], float bj,
                                             float* hrow, int lane) {
    float u0 = 0.f, u1 = 0.f, u2 = 0.f, u3 = 0.f;
#pragma unroll
    for (int q = 0; q < 8; ++q) {
        u0 = fmaf(xt[q].x, wx[4*q+0], u0);
        u1 = fmaf(xt[q].y, wx[4*q+1], u1);
        u2 = fmaf(xt[q].z, wx[4*q+2], u2);
        u3 = fmaf(xt[q].w, wx[4*q+3], u3);
    }
    const float4* hp = (const float4*)hrow;
#pragma unroll
    for (int q = 0; q < 8; ++q) {
        float4 hv = hp[q];
        u0 = fmaf(hv.x, wh[4*q+0], u0);
        u1 = fmaf(hv.y, wh[4*q+1], u1);
        u2 = fmaf(hv.z, wh[4*q+2], u2);
        u3 = fmaf(hv.w, wh[4*q+3], u3);
    }
    float hn = fast_tanh(bj + ((u0 + u1) + (u2 + u3)));
    hrow[lane] = hn;
    return hn;
}

__global__ __launch_bounds__(64) void rnn_seq_kernel(
        const int* __restrict__ x, const float* __restrict__ emb,
        const float* __restrict__ W_rnn, const float* __restrict__ b_rnn,
        const float* __restrict__ W_cls, const float* __restrict__ b_cls,
        float* __restrict__ out) {
    const int lane = threadIdx.x & 31;
    const int grp  = threadIdx.x >> 5;
    const int row  = blockIdx.x * 2 + grp;
    __shared__ float hbuf[2][HH];
    float wx[32], wh[32];
#pragma unroll
    for (int k = 0; k < 32; ++k) {
        wx[k] = W_rnn[k * HH + lane];
        wh[k] = W_rnn[(HH + k) * HH + lane];
    }
    const float bj = b_rnn[lane];
    hbuf[grp][lane] = 0.0f;
    float* hrow = &hbuf[grp][0];
    int i1 = x[1 * BB + row];
    float4 xcur[8], xnxt[8];
    {
        int i0 = x[0 * BB + row];
        const float4* ep = (const float4*)(emb + (size_t)i0 * HH);
#pragma unroll
        for (int q = 0; q < 8; ++q) xcur[q] = ep[q];
    }
    for (int t = 0; t < TT; t += 2) {
        int i2 = x[min(t + 2, TT - 1) * BB + row];
        {
            const float4* ep = (const float4*)(emb + (size_t)i1 * HH);
#pragma unroll
            for (int q = 0; q < 8; ++q) xnxt[q] = ep[q];
        }
        rnn_step_fb(xcur, wx, wh, bj, hrow, lane);
        i1 = x[min(t + 3, TT - 1) * BB + row];
        {
            const float4* ep = (const float4*)(emb + (size_t)i2 * HH);
#pragma unroll
            for (int q = 0; q < 8; ++q) xcur[q] = ep[q];
        }
        rnn_step_fb(xnxt, wx, wh, bj, hrow, lane);
    }
    if (lane < 5) {
        float acc = b_cls[lane];
#pragma unroll
        for (int k = 0; k < 32; ++k)
            acc = fmaf(hrow[k], W_cls[k * 5 + lane], acc);
        out[row * 5 + lane] = acc;
    }
}

extern "C" void kernel_launch(void* const* d_in, const int* in_sizes, int n_in,
                              void* d_out, int out_size, void* d_ws, size_t ws_size,
                              hipStream_t stream) {
    const int*   x     = (const int*)d_in[0];
    const float* emb   = (const float*)d_in[1];
    const float* W_rnn = (const float*)d_in[2];
    const float* b_rnn = (const float*)d_in[3];
    const float* W_cls = (const float*)d_in[4];
    const float* b_cls = (const float*)d_in[5];
    float* out = (float*)d_out;

    const size_t need32 = (size_t)NPAIR * HH * 4;   // 128 MiB
    const size_t need16 = (size_t)NPAIR * HH * 2;   //  64 MiB
    const int pre_blocks = NPAIR / (PPG * 8);       // 8192 blocks x 256 thr

    if (ws_size >= need32) {
        precompute_v3<true><<<pre_blocks, 256, 0, stream>>>(x, emb, W_rnn, b_rnn, d_ws);
        rnn_seq_v3<true><<<BB / 2, 64, 0, stream>>>(d_ws, W_rnn, W_cls, b_cls, out);
    } else if (ws_size >= need16) {
        precompute_v3<false><<<pre_blocks, 256, 0, stream>>>(x, emb, W_rnn, b_rnn, d_ws);
        rnn_seq_v3<false><<<BB / 2, 64, 0, stream>>>(d_ws, W_rnn, W_cls, b_cls, out);
    } else {
        rnn_seq_kernel<<<BB / 2, 64, 0, stream>>>(x, emb, W_rnn, b_rnn, W_cls, b_cls, out);
    }
}